// Round 3
// baseline (854.589 us; speedup 1.0000x reference)
//
#include <hip/hip_runtime.h>
#include <hip/hip_bf16.h>

#define HIDDEN   2048
#define GATEROWS 6144           // 3 * HIDDEN
#define VOCAB    53
#define LAYERS   6
#define NB       1024           // grid blocks; each owns j=bid and j=bid+NB
#define NT       384            // 6 waves

// Persistent fused GRU stack (plain launch; co-residency guaranteed by
// __launch_bounds__(384,6) -> 4 blocks/CU x 256 CU = 1024 = grid).
// Per layer, per block:
//   phase A: gh = w_hh rows · hidden[l]      (no dependency on layer chain)
//   phase B: spin until h_new[l-1] complete  (agent-scope acquire)
//   phase C: gi = w_ih rows · x
//   phase D: thread 0 combines gates, writes h_new[l][j0,j1], signals.
// Wave w<3 handles j0=bid gate w; wave w>=3 handles j1=bid+NB gate w-3.
__global__ __launch_bounds__(NT, 6) void gru_fused(
    const int*   __restrict__ token,
    const float* __restrict__ hidden,   // [6][2048]
    const float* __restrict__ emb,      // [53][2048]
    const float* __restrict__ w_ih,     // [6][6144][2048]
    const float* __restrict__ w_hh,     // [6][6144][2048]
    const float* __restrict__ b_ih,     // [6][6144]
    const float* __restrict__ b_hh,     // [6][6144]
    const float* __restrict__ w_dec,    // [53][2048]
    const float* __restrict__ b_dec,    // [53]
    float*       __restrict__ logits,   // d_out[0..52]
    float*       __restrict__ h_new,    // d_out[53..], [6][2048]
    unsigned int* __restrict__ cnt)     // [8] zeroed each call
{
    const int bid  = blockIdx.x;
    const int tid  = threadIdx.x;
    const int wave = tid >> 6;
    const int lane = tid & 63;

    __shared__ float red[2][12];   // [layer parity][0..5 = gh, 6..11 = gi]

    const int    jw     = (wave < 3) ? bid : bid + NB;
    const int    gw     = (wave < 3) ? wave : wave - 3;
    const size_t rowoff = ((size_t)gw * HIDDEN + (size_t)jw) * HIDDEN;

    const float* x0 = emb + (size_t)token[0] * HIDDEN;

    for (int l = 0; l < LAYERS; ++l) {
        const int p = l & 1;

        // ---- phase A: gh (independent of the layer chain) ----
        {
            const float4* W = (const float4*)(w_hh + (size_t)l * GATEROWS * HIDDEN + rowoff);
            const float4* v = (const float4*)(hidden + (size_t)l * HIDDEN);
            float s = 0.f;
            #pragma unroll
            for (int it = 0; it < 8; ++it) {
                float4 a = W[lane + it * 64];
                float4 b = v[lane + it * 64];
                s += a.x * b.x + a.y * b.y + a.z * b.z + a.w * b.w;
            }
            #pragma unroll
            for (int off = 32; off; off >>= 1) s += __shfl_down(s, off, 64);
            if (lane == 0) red[p][wave] = s;
        }

        // ---- phase B: wait for previous layer's h_new ----
        if (l > 0) {
            if (tid == 0) {
                while (__hip_atomic_load(&cnt[l - 1], __ATOMIC_ACQUIRE,
                                         __HIP_MEMORY_SCOPE_AGENT) < (unsigned)NB)
                    __builtin_amdgcn_s_sleep(2);
            }
        }
        __syncthreads();
        const float* x = (l == 0) ? x0 : h_new + (size_t)(l - 1) * HIDDEN;

        // ---- phase C: gi ----
        {
            const float4* W = (const float4*)(w_ih + (size_t)l * GATEROWS * HIDDEN + rowoff);
            const float4* v = (const float4*)x;
            float s = 0.f;
            #pragma unroll
            for (int it = 0; it < 8; ++it) {
                float4 a = W[lane + it * 64];
                float4 b = v[lane + it * 64];
                s += a.x * b.x + a.y * b.y + a.z * b.z + a.w * b.w;
            }
            #pragma unroll
            for (int off = 32; off; off >>= 1) s += __shfl_down(s, off, 64);
            if (lane == 0) red[p][6 + wave] = s;
        }
        __syncthreads();

        // ---- phase D: combine + signal (thread 0 only) ----
        if (tid == 0) {
            const float* bi = b_ih + (size_t)l * GATEROWS;
            const float* bh = b_hh + (size_t)l * GATEROWS;
            #pragma unroll
            for (int half = 0; half < 2; ++half) {
                int j = bid + half * NB;
                float gi_r = red[p][6 + 3 * half + 0] + bi[j];
                float gi_z = red[p][6 + 3 * half + 1] + bi[j + HIDDEN];
                float gi_n = red[p][6 + 3 * half + 2] + bi[j + 2 * HIDDEN];
                float gh_r = red[p][3 * half + 0] + bh[j];
                float gh_z = red[p][3 * half + 1] + bh[j + HIDDEN];
                float gh_n = red[p][3 * half + 2] + bh[j + 2 * HIDDEN];
                float r = 1.f / (1.f + __expf(-(gi_r + gh_r)));
                float z = 1.f / (1.f + __expf(-(gi_z + gh_z)));
                float n = tanhf(gi_n + r * gh_n);
                h_new[(size_t)l * HIDDEN + j] =
                    (1.f - z) * n + z * hidden[(size_t)l * HIDDEN + j];
            }
            __threadfence();
            __hip_atomic_fetch_add(&cnt[l], 1u, __ATOMIC_RELEASE,
                                   __HIP_MEMORY_SCOPE_AGENT);
        }
        // No block-wide barrier here: layer l+1 phase A writes red[1-p],
        // thread 0 reads red[p]; layer l+2's writes to red[p] can only
        // happen after l+1's phase-B __syncthreads, which thread 0 must
        // reach first (after finishing its red[p] reads).
    }

    // ---- decode: logits = w_dec @ h_new[5] + b_dec ----
    if (bid < VOCAB) {
        if (tid == 0) {
            while (__hip_atomic_load(&cnt[LAYERS - 1], __ATOMIC_ACQUIRE,
                                     __HIP_MEMORY_SCOPE_AGENT) < (unsigned)NB)
                __builtin_amdgcn_s_sleep(2);
        }
        __syncthreads();
        const float4* W = (const float4*)(w_dec + (size_t)bid * HIDDEN);
        const float4* v = (const float4*)(h_new + (size_t)(LAYERS - 1) * HIDDEN);
        float s = 0.f;
        for (int i = tid; i < HIDDEN / 4; i += NT) {
            float4 a = W[i];
            float4 b = v[i];
            s += a.x * b.x + a.y * b.y + a.z * b.z + a.w * b.w;
        }
        #pragma unroll
        for (int off = 32; off; off >>= 1) s += __shfl_down(s, off, 64);
        __shared__ float dred[6];
        if (lane == 0) dred[wave] = s;
        __syncthreads();
        if (tid == 0)
            logits[bid] = dred[0] + dred[1] + dred[2] + dred[3] + dred[4] + dred[5]
                          + b_dec[bid];
    }
}

extern "C" void kernel_launch(void* const* d_in, const int* in_sizes, int n_in,
                              void* d_out, int out_size, void* d_ws, size_t ws_size,
                              hipStream_t stream) {
    const int*   token  = (const int*)  d_in[0];
    const float* hidden = (const float*)d_in[1];
    const float* emb    = (const float*)d_in[2];
    const float* w_ih   = (const float*)d_in[3];
    const float* w_hh   = (const float*)d_in[4];
    const float* b_ih   = (const float*)d_in[5];
    const float* b_hh   = (const float*)d_in[6];
    const float* w_dec  = (const float*)d_in[7];
    const float* b_dec  = (const float*)d_in[8];

    float* out    = (float*)d_out;
    float* logits = out;            // [53]
    float* h_new  = out + VOCAB;    // [6][2048]

    unsigned int* cnt = (unsigned int*)d_ws;
    hipMemsetAsync(cnt, 0, 8 * sizeof(unsigned int), stream);

    gru_fused<<<dim3(NB), dim3(NT), 0, stream>>>(
        token, hidden, emb, w_ih, w_hh, b_ih, b_hh,
        w_dec, b_dec, logits, h_new, cnt);
}

// Round 5
// 299.084 us; speedup vs baseline: 2.8573x; 2.8573x over previous
//
#include <hip/hip_runtime.h>
#include <hip/hip_bf16.h>

#define HIDDEN   2048
#define GROWS    6144            // 3 * HIDDEN
#define VOCAB    53
#define LAYERS   6
#define NBLK     512             // blocks; 2 per CU
#define NT       768             // 12 waves = 3 gates x 4 j-slots
#define JPB      4               // j's per block = HIDDEN / NBLK

// ws layout (bytes):
//   [0, 49152)        float h_work[6][2048]   (aligned working hidden state)
//   [49152, ...)      barrier counters: per layer 32 sub-counters (64B apart),
//                     then per layer 1 master counter (64B apart)
#define WS_H_OFF    0
#define WS_SUB_OFF  49152
#define SUB_LINES   32
#define BLK_PER_SUB (NBLK / SUB_LINES)    // 16
#define WS_MST_OFF  (WS_SUB_OFF + SUB_LINES * 64 * LAYERS)
#define WS_CTR_BYTES (SUB_LINES * 64 * LAYERS + 64 * LAYERS)

// Persistent fused GRU stack; plain launch, co-residency by construction
// (512 blocks x 12 waves = 24 waves/CU on 256 CUs).
// Per layer: A) gh = w_hh row · hidden[l] (chain-independent, overlaps the
// barrier), B) relaxed-poll master counter + one acquire fence, C) gi =
// w_ih row · x, D) wave 0 combines gates, stores h, hierarchical release.
__global__ __launch_bounds__(NT, 6) void gru_fused(
    const int*   __restrict__ token,
    const float* __restrict__ hidden,   // [6][2048]
    const float* __restrict__ emb,      // [53][2048]
    const float* __restrict__ w_ih,     // [6][6144][2048]
    const float* __restrict__ w_hh,     // [6][6144][2048]
    const float* __restrict__ b_ih,     // [6][6144]
    const float* __restrict__ b_hh,     // [6][6144]
    const float* __restrict__ w_dec,    // [53][2048]
    const float* __restrict__ b_dec,    // [53]
    float*       __restrict__ out,      // [53 logits][6*2048 h_new]
    char*        __restrict__ ws)
{
    const int bid  = blockIdx.x;
    const int tid  = threadIdx.x;
    const int wave = tid >> 6;
    const int lane = tid & 63;
    const int g    = wave >> 2;          // gate 0..2
    const int k    = wave & 3;           // j slot 0..3
    const int j    = bid + NBLK * k;

    float*    h_work = (float*)(ws + WS_H_OFF);
    unsigned* subc   = (unsigned*)(ws + WS_SUB_OFF);
    unsigned* mstc   = (unsigned*)(ws + WS_MST_OFF);

    __shared__ float rgh[2][3][JPB];
    __shared__ float rgi[2][3][JPB];

    const size_t rowoff = ((size_t)g * HIDDEN + (size_t)j) * HIDDEN;
    const float* x0 = emb + (size_t)token[0] * HIDDEN;

    for (int l = 0; l < LAYERS; ++l) {
        const int p = l & 1;

        // ---- phase A: gh (independent of layer chain; overlaps barrier) ----
        {
            const float4* W = (const float4*)(w_hh + (size_t)l * GROWS * HIDDEN + rowoff);
            const float4* v = (const float4*)(hidden + (size_t)l * HIDDEN);
            float s = 0.f;
            #pragma unroll
            for (int it = 0; it < 8; ++it) {
                float4 a = W[lane + 64 * it];
                float4 b = v[lane + 64 * it];
                s += a.x * b.x + a.y * b.y + a.z * b.z + a.w * b.w;
            }
            #pragma unroll
            for (int o = 32; o; o >>= 1) s += __shfl_down(s, o, 64);
            if (lane == 0) rgh[p][g][k] = s;
        }

        // ---- phase B: wait for h_new[l-1] (relaxed poll, single fence) ----
        if (l > 0 && tid == 0) {
            while (__hip_atomic_load(&mstc[(l - 1) * 16], __ATOMIC_RELAXED,
                                     __HIP_MEMORY_SCOPE_AGENT) < (unsigned)SUB_LINES)
                __builtin_amdgcn_s_sleep(8);
            __builtin_amdgcn_fence(__ATOMIC_ACQUIRE, "agent");
        }
        __syncthreads();
        const float* x = (l == 0) ? x0 : h_work + (size_t)(l - 1) * HIDDEN;

        // ---- phase C: gi ----
        {
            const float4* W = (const float4*)(w_ih + (size_t)l * GROWS * HIDDEN + rowoff);
            const float4* v = (const float4*)x;
            float s = 0.f;
            #pragma unroll
            for (int it = 0; it < 8; ++it) {
                float4 a = W[lane + 64 * it];
                float4 b = v[lane + 64 * it];
                s += a.x * b.x + a.y * b.y + a.z * b.z + a.w * b.w;
            }
            #pragma unroll
            for (int o = 32; o; o >>= 1) s += __shfl_down(s, o, 64);
            if (lane == 0) rgi[p][g][k] = s;
        }
        __syncthreads();

        // ---- phase D: combine + hierarchical release (wave 0 only) ----
        if (wave == 0) {
            if (lane < JPB) {
                const int jj = bid + NBLK * lane;
                const float* bi = b_ih + (size_t)l * GROWS;
                const float* bh = b_hh + (size_t)l * GROWS;
                float gir = rgi[p][0][lane] + bi[jj];
                float giz = rgi[p][1][lane] + bi[jj + HIDDEN];
                float gin = rgi[p][2][lane] + bi[jj + 2 * HIDDEN];
                float ghr = rgh[p][0][lane] + bh[jj];
                float ghz = rgh[p][1][lane] + bh[jj + HIDDEN];
                float ghn = rgh[p][2][lane] + bh[jj + 2 * HIDDEN];
                float r = 1.f / (1.f + __expf(-(gir + ghr)));
                float z = 1.f / (1.f + __expf(-(giz + ghz)));
                float n = tanhf(gin + r * ghn);
                float hv = (1.f - z) * n + z * hidden[(size_t)l * HIDDEN + jj];
                h_work[(size_t)l * HIDDEN + jj] = hv;           // aligned working copy
                out[VOCAB + (size_t)l * HIDDEN + jj] = hv;      // output mirror
            }
            if (lane == 0) {
                // release: sub-line add (ACQ_REL chains happens-before), last
                // arrival of the 16 bumps the master (32 adds/layer total).
                unsigned old = __hip_atomic_fetch_add(
                    &subc[(l * SUB_LINES + (bid & (SUB_LINES - 1))) * 16], 1u,
                    __ATOMIC_ACQ_REL, __HIP_MEMORY_SCOPE_AGENT);
                if (old == (unsigned)(BLK_PER_SUB - 1))
                    __hip_atomic_fetch_add(&mstc[l * 16], 1u,
                                           __ATOMIC_ACQ_REL, __HIP_MEMORY_SCOPE_AGENT);
            }
        }
        // No trailing barrier: next layer's phase A writes rgh[1-p]; wave 0
        // still reads rgh/rgi[p]; layer l+2 (which reuses [p]) can't start
        // until l+1's phase-B __syncthreads, which wave 0 reaches only after
        // finishing phase D of layer l.
    }

    // ---- decode: logits = w_dec @ h_work[5] + b_dec ----
    if (bid < VOCAB) {
        if (tid == 0) {
            while (__hip_atomic_load(&mstc[(LAYERS - 1) * 16], __ATOMIC_RELAXED,
                                     __HIP_MEMORY_SCOPE_AGENT) < (unsigned)SUB_LINES)
                __builtin_amdgcn_s_sleep(8);
            __builtin_amdgcn_fence(__ATOMIC_ACQUIRE, "agent");
        }
        __syncthreads();
        const float4* W = (const float4*)(w_dec + (size_t)bid * HIDDEN);
        const float4* v = (const float4*)(h_work + (size_t)(LAYERS - 1) * HIDDEN);
        float s = 0.f;
        if (tid < 512) {
            float4 a = W[tid];
            float4 b = v[tid];
            s = a.x * b.x + a.y * b.y + a.z * b.z + a.w * b.w;
        }
        #pragma unroll
        for (int o = 32; o; o >>= 1) s += __shfl_down(s, o, 64);
        __shared__ float dred[12];
        if (lane == 0) dred[wave] = s;
        __syncthreads();
        if (tid == 0) {
            float t = 0.f;
            #pragma unroll
            for (int w = 0; w < 8; ++w) t += dred[w];
            out[bid] = t + b_dec[bid];
        }
    }
}

extern "C" void kernel_launch(void* const* d_in, const int* in_sizes, int n_in,
                              void* d_out, int out_size, void* d_ws, size_t ws_size,
                              hipStream_t stream) {
    const int*   token  = (const int*)  d_in[0];
    const float* hidden = (const float*)d_in[1];
    const float* emb    = (const float*)d_in[2];
    const float* w_ih   = (const float*)d_in[3];
    const float* w_hh   = (const float*)d_in[4];
    const float* b_ih   = (const float*)d_in[5];
    const float* b_hh   = (const float*)d_in[6];
    const float* w_dec  = (const float*)d_in[7];
    const float* b_dec  = (const float*)d_in[8];

    float* out = (float*)d_out;
    char*  ws  = (char*)d_ws;

    // zero the barrier counters (harness does not re-poison between replays)
    (void)hipMemsetAsync(ws + WS_SUB_OFF, 0, WS_CTR_BYTES, stream);

    gru_fused<<<dim3(NBLK), dim3(NT), 0, stream>>>(
        token, hidden, emb, w_ih, w_hh, b_ih, b_hh,
        w_dec, b_dec, out, ws);
}

// Round 6
// 130.861 us; speedup vs baseline: 6.5305x; 2.2855x over previous
//
#include <hip/hip_runtime.h>
#include <hip/hip_bf16.h>

#define HIDDEN   2048
#define GROWS    6144            // 3 * HIDDEN
#define VOCAB    53
#define LAYERS   6
#define NBLK     512             // blocks; 2 per CU (12 waves each = 24 waves/CU)
#define NT       768             // 12 waves = 3 gates x 4 j-slots
#define JPB      4               // j's per block = HIDDEN / NBLK

typedef unsigned long long ull;

// ws layout (bytes):
//   [0, 49152)   float h_work[6][2048]  (synchronization copy of hidden state;
//                written/read ONLY via relaxed agent-scope atomics -> coherence point)
//   [49152, ..)  per layer: 32 sub-counters (64B apart), then 1 master/layer (64B apart)
#define WS_H_OFF     0
#define WS_SUB_OFF   49152
#define SUB_LINES    32
#define BLK_PER_SUB  (NBLK / SUB_LINES)   // 16
#define WS_MST_OFF   (WS_SUB_OFF + SUB_LINES * 64 * LAYERS)
#define WS_CTR_BYTES (SUB_LINES * 64 * LAYERS + 64 * LAYERS)

// Persistent fused GRU stack. NO acquire/release anywhere (agent fences on
// gfx950 emit whole-L2 writeback/invalidate -> R5's 0.9 TB/s collapse).
// Message passing instead: h values travel through the coherence point via
// relaxed bypass atomics; ordering h-stores -> counter bump is a raw
// s_waitcnt vmcnt(0) (store ack == performed at coherence point); counter
// RMW acks chain the rest (hierarchical, so master implies all 512 h's).
__global__ __launch_bounds__(NT, 6) void gru_fused(
    const int*   __restrict__ token,
    const float* __restrict__ hidden,   // [6][2048]
    const float* __restrict__ emb,      // [53][2048]
    const float* __restrict__ w_ih,     // [6][6144][2048]
    const float* __restrict__ w_hh,     // [6][6144][2048]
    const float* __restrict__ b_ih,     // [6][6144]
    const float* __restrict__ b_hh,     // [6][6144]
    const float* __restrict__ w_dec,    // [53][2048]
    const float* __restrict__ b_dec,    // [53]
    float*       __restrict__ out,      // [53 logits][6*2048 h_new]
    char*        __restrict__ ws)
{
    const int bid  = blockIdx.x;
    const int tid  = threadIdx.x;
    const int wave = tid >> 6;
    const int lane = tid & 63;
    const int g    = wave >> 2;          // gate 0..2
    const int k    = wave & 3;           // j slot 0..3
    const int j    = bid + NBLK * k;

    float*    h_work = (float*)(ws + WS_H_OFF);
    unsigned* subc   = (unsigned*)(ws + WS_SUB_OFF);
    unsigned* mstc   = (unsigned*)(ws + WS_MST_OFF);

    __shared__ float xlds[HIDDEN];       // staged x vector (8 KB)
    __shared__ float rgh[2][3][JPB];
    __shared__ float rgi[2][3][JPB];

    const size_t rowoff = ((size_t)g * HIDDEN + (size_t)j) * HIDDEN;
    const float* x0 = emb + (size_t)token[0] * HIDDEN;

    for (int l = 0; l < LAYERS; ++l) {
        const int p = l & 1;

        // ---- phase A: gh = w_hh row · hidden[l]  (chain-independent) ----
        {
            const float4* W = (const float4*)(w_hh + (size_t)l * GROWS * HIDDEN + rowoff);
            const float4* v = (const float4*)(hidden + (size_t)l * HIDDEN);
            float s = 0.f;
            #pragma unroll
            for (int it = 0; it < 8; ++it) {
                float4 a = W[lane + 64 * it];
                float4 b = v[lane + 64 * it];
                s += a.x * b.x + a.y * b.y + a.z * b.z + a.w * b.w;
            }
            #pragma unroll
            for (int o = 32; o; o >>= 1) s += __shfl_down(s, o, 64);
            if (lane == 0) rgh[p][g][k] = s;
        }

        // ---- prefetch w_ih row into registers (keeps HBM busy across barrier) ----
        float4 wf[8];
        {
            const float4* W = (const float4*)(w_ih + (size_t)l * GROWS * HIDDEN + rowoff);
            #pragma unroll
            for (int it = 0; it < 8; ++it) wf[it] = W[lane + 64 * it];
        }

        // ---- phase B: relaxed poll of master counter (no fence!) ----
        if (l > 0 && tid == 0) {
            while (__hip_atomic_load(&mstc[(l - 1) * 16], __ATOMIC_RELAXED,
                                     __HIP_MEMORY_SCOPE_AGENT) < (unsigned)SUB_LINES)
                __builtin_amdgcn_s_sleep(8);
        }
        __syncthreads();

        // ---- stage x into LDS ----
        if (l == 0) {
            const ull* src = (const ull*)x0;
            for (int i = tid; i < HIDDEN / 2; i += NT)
                ((ull*)xlds)[i] = src[i];
        } else {
            const ull* src = (const ull*)(h_work + (size_t)(l - 1) * HIDDEN);
            for (int i = tid; i < HIDDEN / 2; i += NT)
                ((ull*)xlds)[i] = __hip_atomic_load(&src[i], __ATOMIC_RELAXED,
                                                    __HIP_MEMORY_SCOPE_AGENT);
        }
        __syncthreads();

        // ---- phase C: gi = prefetched w_ih row · x ----
        {
            const float4* xl = (const float4*)xlds;
            float s = 0.f;
            #pragma unroll
            for (int it = 0; it < 8; ++it) {
                float4 b = xl[lane + 64 * it];
                s += wf[it].x * b.x + wf[it].y * b.y + wf[it].z * b.z + wf[it].w * b.w;
            }
            #pragma unroll
            for (int o = 32; o; o >>= 1) s += __shfl_down(s, o, 64);
            if (lane == 0) rgi[p][g][k] = s;
        }
        __syncthreads();

        // ---- phase D: gates + h publish + hierarchical relaxed release ----
        if (wave == 0) {
            if (lane < JPB) {
                const int jj = bid + NBLK * lane;
                const float* bi = b_ih + (size_t)l * GROWS;
                const float* bh = b_hh + (size_t)l * GROWS;
                float gir = rgi[p][0][lane] + bi[jj];
                float giz = rgi[p][1][lane] + bi[jj + HIDDEN];
                float gin = rgi[p][2][lane] + bi[jj + 2 * HIDDEN];
                float ghr = rgh[p][0][lane] + bh[jj];
                float ghz = rgh[p][1][lane] + bh[jj + HIDDEN];
                float ghn = rgh[p][2][lane] + bh[jj + 2 * HIDDEN];
                float r = 1.f / (1.f + __expf(-(gir + ghr)));
                float z = 1.f / (1.f + __expf(-(giz + ghz)));
                float n = tanhf(gin + r * ghn);
                float hv = (1.f - z) * n + z * hidden[(size_t)l * HIDDEN + jj];
                // bypass store -> coherence point (no cache maintenance)
                __hip_atomic_store(&h_work[(size_t)l * HIDDEN + jj], hv,
                                   __ATOMIC_RELAXED, __HIP_MEMORY_SCOPE_AGENT);
                out[VOCAB + (size_t)l * HIDDEN + jj] = hv;   // plain mirror for d_out
            }
            // store acks == performed at coherence point; then relaxed bumps
            asm volatile("s_waitcnt vmcnt(0)" ::: "memory");
            if (lane == 0) {
                unsigned old = __hip_atomic_fetch_add(
                    &subc[(l * SUB_LINES + (bid & (SUB_LINES - 1))) * 16], 1u,
                    __ATOMIC_RELAXED, __HIP_MEMORY_SCOPE_AGENT);
                if (old == (unsigned)(BLK_PER_SUB - 1))
                    __hip_atomic_fetch_add(&mstc[l * 16], 1u,
                                           __ATOMIC_RELAXED, __HIP_MEMORY_SCOPE_AGENT);
            }
        }
        // No trailing barrier: next layer's A/prefetch write rgh[1-p]/wf only;
        // wave 0 reads rgh/rgi[p]; the [p] buffers are next written at layer
        // l+2, which is gated by l+1's phase-B __syncthreads that wave 0
        // joins only after finishing phase D here.
    }

    // ---- decode: logits = w_dec @ h[5] + b_dec (blocks 0..52) ----
    if (bid < VOCAB) {
        if (tid == 0) {
            while (__hip_atomic_load(&mstc[(LAYERS - 1) * 16], __ATOMIC_RELAXED,
                                     __HIP_MEMORY_SCOPE_AGENT) < (unsigned)SUB_LINES)
                __builtin_amdgcn_s_sleep(8);
        }
        __syncthreads();
        {
            const ull* src = (const ull*)(h_work + (size_t)(LAYERS - 1) * HIDDEN);
            for (int i = tid; i < HIDDEN / 2; i += NT)
                ((ull*)xlds)[i] = __hip_atomic_load(&src[i], __ATOMIC_RELAXED,
                                                    __HIP_MEMORY_SCOPE_AGENT);
        }
        __syncthreads();
        const float4* W  = (const float4*)(w_dec + (size_t)bid * HIDDEN);
        const float4* xl = (const float4*)xlds;
        float s = 0.f;
        if (tid < 512) {
            float4 a = W[tid];
            float4 b = xl[tid];
            s = a.x * b.x + a.y * b.y + a.z * b.z + a.w * b.w;
        }
        #pragma unroll
        for (int o = 32; o; o >>= 1) s += __shfl_down(s, o, 64);
        __shared__ float dred[12];
        if (lane == 0) dred[wave] = s;
        __syncthreads();
        if (tid == 0) {
            float t = 0.f;
            #pragma unroll
            for (int w = 0; w < 12; ++w) t += dred[w];
            out[bid] = t + b_dec[bid];
        }
    }
}

extern "C" void kernel_launch(void* const* d_in, const int* in_sizes, int n_in,
                              void* d_out, int out_size, void* d_ws, size_t ws_size,
                              hipStream_t stream) {
    const int*   token  = (const int*)  d_in[0];
    const float* hidden = (const float*)d_in[1];
    const float* emb    = (const float*)d_in[2];
    const float* w_ih   = (const float*)d_in[3];
    const float* w_hh   = (const float*)d_in[4];
    const float* b_ih   = (const float*)d_in[5];
    const float* b_hh   = (const float*)d_in[6];
    const float* w_dec  = (const float*)d_in[7];
    const float* b_dec  = (const float*)d_in[8];

    float* out = (float*)d_out;
    char*  ws  = (char*)d_ws;

    // zero the barrier counters (graph replays reuse ws)
    (void)hipMemsetAsync(ws + WS_SUB_OFF, 0, WS_CTR_BYTES, stream);

    gru_fused<<<dim3(NBLK), dim3(NT), 0, stream>>>(
        token, hidden, emb, w_ih, w_hh, b_ih, b_hh,
        w_dec, b_dec, out, ws);
}